// Round 1
// baseline (13972.899 us; speedup 1.0000x reference)
//
#include <hip/hip_runtime.h>
#include <hip/hip_bf16.h>

// SignalDecoder: 2-layer bidirectional LSTM, 52 steps, B=1024, HID=256.
// Strategy (round 1): persistent batch-partitioned kernel.
//   - 64 blocks x 1024 threads (16 waves); block owns 16 batch rows for all 52 steps.
//   - No inter-block sync needed (batch rows independent); __syncthreads between stages.
//   - Kernel 1 packs fp32 weights -> bf16 MFMA-fragment layout in d_ws (runs every call).
//   - bf16 MFMA 16x16x32, fp32 accum; cell state c kept fp32 in registers.
// LDS: Xbuf = [h0f|h0b] (layer1 input AND layer0 h-state), Ybuf = [h1f|h1b] (= y,
// layer0 input AND layer1 h-state). Padded stride 520 to break ds_read_b128 bank aliasing.

#define NSTEPS 52
#define LSTRIDE 520   // 512 + 8 bf16 pad

typedef __attribute__((ext_vector_type(8))) short bf16x8;
typedef __attribute__((ext_vector_type(4))) float f32x4;
typedef __attribute__((ext_vector_type(4))) unsigned int u32x4;

__device__ __forceinline__ unsigned short f2bf(float f) {
  union { float f; unsigned int u; } v; v.f = f;
  unsigned int r = v.u + 0x7fffu + ((v.u >> 16) & 1u);  // RNE
  return (unsigned short)(r >> 16);
}

// Pack weights: for cell c (0=l0f,1=l0b,2=l1f,3=l1b), Wcat = [W_ih (K=512) | W_hh (K=256)],
// fragment chunk (c, n16, kc): lane l holds W[n16*16 + (l&15)][kc*32 + (l>>4)*8 + j], j=0..7.
// chunk byte offset = ((c*64 + n16)*24 + kc)*1024 + lane*16. Also bsum[c*1024+n] = b_ih+b_hh.
__global__ void wpack_kernel(const float* __restrict__ Wih0, const float* __restrict__ Whh0,
                             const float* __restrict__ bih0, const float* __restrict__ bhh0,
                             const float* __restrict__ Wih1, const float* __restrict__ Whh1,
                             const float* __restrict__ bih1, const float* __restrict__ bhh1,
                             unsigned short* __restrict__ wpack, float* __restrict__ bsum) {
  int tid = blockIdx.x * 256 + threadIdx.x;  // exactly 4*64*24*64 = 393216 threads
  int lane = tid & 63;
  int chunk = tid >> 6;
  int kc = chunk % 24;
  int cn = chunk / 24;
  int n16 = cn & 63;
  int c = cn >> 6;
  int n = n16 * 16 + (lane & 15);
  int k0 = kc * 32 + (lane >> 4) * 8;
  const float* Wih = (c < 2) ? Wih0 : Wih1;
  const float* Whh = (c < 2) ? Whh0 : Whh1;
  int d = c & 1;
  unsigned short tmp[8];
#pragma unroll
  for (int j = 0; j < 8; j++) {
    int k = k0 + j;  // 8-runs never straddle k=512 (multiples of 8)
    float val = (k < 512) ? Wih[(d * 1024 + n) * 512 + k]
                          : Whh[(d * 1024 + n) * 256 + (k - 512)];
    tmp[j] = f2bf(val);
  }
  *(u32x4*)(wpack + (size_t)tid * 8) = *(const u32x4*)tmp;
  if (tid < 4096) {
    int c2 = tid >> 10, n2 = tid & 1023;
    float b = (c2 < 2) ? (bih0[(c2 & 1) * 1024 + n2] + bhh0[(c2 & 1) * 1024 + n2])
                       : (bih1[(c2 & 1) * 1024 + n2] + bhh1[(c2 & 1) * 1024 + n2]);
    bsum[tid] = b;
  }
}

__device__ __forceinline__ float sigm(float x) { return 1.f / (1.f + __expf(-x)); }
__device__ __forceinline__ float tanh_f(float x) { return 2.f / (1.f + __expf(-2.f * x)) - 1.f; }

__global__ __launch_bounds__(1024) void lstm_kernel(
    const float* __restrict__ code,
    const unsigned short* __restrict__ wpack,
    const float* __restrict__ bsum,
    float* __restrict__ out) {
  __shared__ unsigned short Xbuf[16 * LSTRIDE];  // [h0f | h0b]
  __shared__ unsigned short Ybuf[16 * LSTRIDE];  // [h1f | h1b] == y

  const int tid = threadIdx.x;
  const int lane = tid & 63;
  const int w = tid >> 6;        // wave 0..15
  const int half = w >> 3;       // which cell within stage (fwd/bwd)
  const int hs = w & 7;          // 32-wide hidden slice
  const int rowbase = blockIdx.x * 16;
  const int lrow = (lane >> 4) * 4;            // + r -> MFMA D row
  const int lcol = hs * 32 + (lane & 15);      // + tt*16 -> hidden index

  // --- init LDS from code: h0 = code[:,0,cell,:]; cells 0,1 -> Xbuf, cells 2,3 -> Ybuf
  for (int idx = tid; idx < 16 * 1024; idx += 1024) {
    int row = idx >> 10, col = idx & 1023;
    int cs = col >> 8, hid = col & 255;
    unsigned short b = f2bf(code[(rowbase + row) * 2048 + cs * 256 + hid]);
    if (cs < 2) Xbuf[row * LSTRIDE + col] = b;
    else        Ybuf[row * LSTRIDE + (col - 512)] = b;
  }

  // --- c0 into registers + bias sums; [stage][tt][...]
  float creg[2][2][4];
  float brg[2][2][4];
#pragma unroll
  for (int s = 0; s < 2; s++) {
    int cell = s * 2 + half;
#pragma unroll
    for (int tt = 0; tt < 2; tt++) {
      int colh = lcol + tt * 16;
#pragma unroll
      for (int r = 0; r < 4; r++)
        creg[s][tt][r] = code[(rowbase + lrow + r) * 2048 + 1024 + cell * 256 + colh];
#pragma unroll
      for (int g = 0; g < 4; g++)
        brg[s][tt][g] = bsum[cell * 1024 + g * 256 + colh];
    }
  }
  __syncthreads();

  const int arow = (lane & 15) * LSTRIDE;
  const int aoff = (lane >> 4) * 8;

  for (int step = 0; step < NSTEPS; step++) {
#pragma unroll
    for (int s = 0; s < 2; s++) {
      const unsigned short* __restrict__ Xsrc = (s == 0) ? Ybuf : Xbuf;               // k<512
      const unsigned short* __restrict__ Hsrc = ((s == 0) ? Xbuf : Ybuf) + half * 256; // k>=512
      unsigned short* __restrict__ Dst = (s == 0) ? Xbuf : Ybuf;
      const int cell = s * 2 + half;
      const unsigned short* __restrict__ wb = wpack + (size_t)cell * 786432 + (size_t)lane * 8;
      float hval[2][4];

#pragma unroll
      for (int tt = 0; tt < 2; tt++) {
        f32x4 acc0 = {0.f, 0.f, 0.f, 0.f};
        f32x4 acc1 = acc0, acc2 = acc0, acc3 = acc0;
        const int wot = (hs * 2 + tt) * 12288;  // n16 = g*16 + hs*2 + tt; stride 24*512

        // x-part (K 0..511): skipped at step 0 stage 0 since y_0 == 0
        if (!(step == 0 && s == 0)) {
          for (int kc = 0; kc < 16; kc++) {
            bf16x8 af = *(const bf16x8*)(Xsrc + arow + kc * 32 + aoff);
            int wo = wot + kc * 512;
            bf16x8 b0 = *(const bf16x8*)(wb + wo);
            bf16x8 b1 = *(const bf16x8*)(wb + wo + 16 * 12288);
            bf16x8 b2 = *(const bf16x8*)(wb + wo + 32 * 12288);
            bf16x8 b3 = *(const bf16x8*)(wb + wo + 48 * 12288);
            acc0 = __builtin_amdgcn_mfma_f32_16x16x32_bf16(af, b0, acc0, 0, 0, 0);
            acc1 = __builtin_amdgcn_mfma_f32_16x16x32_bf16(af, b1, acc1, 0, 0, 0);
            acc2 = __builtin_amdgcn_mfma_f32_16x16x32_bf16(af, b2, acc2, 0, 0, 0);
            acc3 = __builtin_amdgcn_mfma_f32_16x16x32_bf16(af, b3, acc3, 0, 0, 0);
          }
        }
        // h-part (K 512..767)
        for (int kc = 16; kc < 24; kc++) {
          bf16x8 af = *(const bf16x8*)(Hsrc + arow + (kc - 16) * 32 + aoff);
          int wo = wot + kc * 512;
          bf16x8 b0 = *(const bf16x8*)(wb + wo);
          bf16x8 b1 = *(const bf16x8*)(wb + wo + 16 * 12288);
          bf16x8 b2 = *(const bf16x8*)(wb + wo + 32 * 12288);
          bf16x8 b3 = *(const bf16x8*)(wb + wo + 48 * 12288);
          acc0 = __builtin_amdgcn_mfma_f32_16x16x32_bf16(af, b0, acc0, 0, 0, 0);
          acc1 = __builtin_amdgcn_mfma_f32_16x16x32_bf16(af, b1, acc1, 0, 0, 0);
          acc2 = __builtin_amdgcn_mfma_f32_16x16x32_bf16(af, b2, acc2, 0, 0, 0);
          acc3 = __builtin_amdgcn_mfma_f32_16x16x32_bf16(af, b3, acc3, 0, 0, 0);
        }

        // gate epilogue: i,f,g,o -> c,h (PyTorch gate order)
#pragma unroll
        for (int r = 0; r < 4; r++) {
          float iv = sigm(acc0[r] + brg[s][tt][0]);
          float fv = sigm(acc1[r] + brg[s][tt][1]);
          float gv = tanh_f(acc2[r] + brg[s][tt][2]);
          float ov = sigm(acc3[r] + brg[s][tt][3]);
          float c2 = fv * creg[s][tt][r] + iv * gv;
          creg[s][tt][r] = c2;
          float hv = ov * tanh_f(c2);
          hval[tt][r] = hv;
          if (s == 1)  // y output, fp32 (pre-bf16-rounding), [B, 52, 512]
            out[((size_t)(rowbase + lrow + r) * NSTEPS + step) * 512 + half * 256 + lcol + tt * 16] = hv;
        }
      }

      __syncthreads();  // all reads of Dst (h-state) done before overwrite
#pragma unroll
      for (int tt = 0; tt < 2; tt++)
#pragma unroll
        for (int r = 0; r < 4; r++)
          Dst[(lrow + r) * LSTRIDE + half * 256 + lcol + tt * 16] = f2bf(hval[tt][r]);
      __syncthreads();
    }
  }
}

extern "C" void kernel_launch(void* const* d_in, const int* in_sizes, int n_in,
                              void* d_out, int out_size, void* d_ws, size_t ws_size,
                              hipStream_t stream) {
  const float* code = (const float*)d_in[0];
  // d_in[1] = x  -- unused by the reference
  const float* Wih0 = (const float*)d_in[2];
  const float* Whh0 = (const float*)d_in[3];
  const float* bih0 = (const float*)d_in[4];
  const float* bhh0 = (const float*)d_in[5];
  const float* Wih1 = (const float*)d_in[6];
  const float* Whh1 = (const float*)d_in[7];
  const float* bih1 = (const float*)d_in[8];
  const float* bhh1 = (const float*)d_in[9];

  unsigned short* wpack = (unsigned short*)d_ws;                  // 6,291,456 B
  float* bsum = (float*)((char*)d_ws + 6291456);                  // 16 KB

  wpack_kernel<<<1536, 256, 0, stream>>>(Wih0, Whh0, bih0, bhh0,
                                         Wih1, Whh1, bih1, bhh1, wpack, bsum);
  lstm_kernel<<<64, 1024, 0, stream>>>(code, wpack, bsum, (float*)d_out);
}